// Round 2
// 941.019 us; speedup vs baseline: 1.0591x; 1.0591x over previous
//
#include <hip/hip_runtime.h>
#include <hip/hip_bf16.h>
#include <cstdint>
#include <cstddef>

// Problem constants (from reference): E,D,H1,H2,O,B
#define E_  100
#define D_  2048
#define H1_ 512
#define H2_ 256
#define B_  1024

typedef __bf16 bf16x8 __attribute__((ext_vector_type(8)));
typedef float  f32x4  __attribute__((ext_vector_type(4)));

typedef __attribute__((address_space(1))) void gvoid;
typedef __attribute__((address_space(3))) void lvoid;

__device__ __forceinline__ unsigned short f2bf(float f){
    union { float f; unsigned int u; } x; x.f = f;
    unsigned int r = x.u + 0x7fffu + ((x.u >> 16) & 1u);   // RNE
    return (unsigned short)(r >> 16);
}
__device__ __forceinline__ float bf2f(unsigned int u){
    union { unsigned int i; float f; } x; x.i = u << 16; return x.f;
}

// ---------------- x fp32 -> bf16 convert, element-wise ----------------
__global__ __launch_bounds__(256) void cvt_x_kernel(const float* __restrict__ x,
                                                    unsigned short* __restrict__ xb){
    int i = blockIdx.x * 256 + threadIdx.x;
    float4 v = ((const float4*)x)[i];
    ushort4 o;
    o.x = f2bf(v.x); o.y = f2bf(v.y); o.z = f2bf(v.z); o.w = f2bf(v.w);
    ((ushort4*)xb)[i] = o;
}

// ---------------- batched transpose + convert: src fp32 [E][R][C] -> dst bf16 [E][C][R] ----
__global__ __launch_bounds__(256) void transpose_cvt_kernel(const float* __restrict__ src,
                                                            unsigned short* __restrict__ dst,
                                                            int R, int C){
    __shared__ unsigned int T[64 * 32];
    const int e  = blockIdx.z;
    const int r0 = blockIdx.y * 64, c0 = blockIdx.x * 64;
    const float* s = src + (size_t)e * R * C;
    unsigned short* d = dst + (size_t)e * R * C;
    const int t  = threadIdx.x;
    const int c4 = (t & 15) * 4;
    #pragma unroll
    for (int pass = 0; pass < 2; ++pass){
        const int rp = (t >> 4) + pass * 16;
        const int r  = rp * 2;
        const float4 va = *(const float4*)(s + (size_t)(r0 + r)     * C + c0 + c4);
        const float4 vb = *(const float4*)(s + (size_t)(r0 + r + 1) * C + c0 + c4);
        const float aa[4] = {va.x, va.y, va.z, va.w};
        const float bb[4] = {vb.x, vb.y, vb.z, vb.w};
        #pragma unroll
        for (int i = 0; i < 4; ++i){
            const int c = c4 + i;
            const unsigned int pk = (unsigned int)f2bf(aa[i]) | ((unsigned int)f2bf(bb[i]) << 16);
            T[c * 32 + (rp ^ (c & 31))] = pk;
        }
    }
    __syncthreads();
    const int c  = t >> 2;
    const int j0 = (t & 3) * 8;
    unsigned int tmp[8];
    #pragma unroll
    for (int j = 0; j < 8; ++j)
        tmp[j] = T[c * 32 + ((j0 + j) ^ (c & 31))];
    unsigned short* drow = d + (size_t)(c0 + c) * R + r0 + j0 * 2;
    ((uint4*)drow)[0] = make_uint4(tmp[0], tmp[1], tmp[2], tmp[3]);
    ((uint4*)drow)[1] = make_uint4(tmp[4], tmp[5], tmp[6], tmp[7]);
}

// ---------------- 128x128 bf16 MFMA GEMM (kept for layer 2) ----------------
__global__ __launch_bounds__(256) void gemm_bt_relu(const unsigned short* __restrict__ A,
                                                    long long aEstride,
                                                    const unsigned short* __restrict__ Bt,
                                                    const float* __restrict__ bias,
                                                    unsigned short* __restrict__ Cout,
                                                    int M, int N, int K){
    __shared__ unsigned short As[128 * 32];
    __shared__ unsigned short Bs[128 * 32];
    const int e  = blockIdx.z;
    const int m0 = blockIdx.y * 128, n0 = blockIdx.x * 128;
    const int t = threadIdx.x, lane = t & 63, wid = t >> 6;
    const int wm = wid >> 1, wn = wid & 1;

    const unsigned short* Ae = A + (size_t)e * (size_t)aEstride + (size_t)m0 * K;
    const unsigned short* Be = Bt + (size_t)e * (size_t)N * K + (size_t)n0 * K;

    const int ch0 = wid * 128 + lane;
    const int r0s = ch0 >> 2, k0s = (((ch0 & 3) ^ ((ch0 >> 3) & 3)) * 8);
    const int ch1 = ch0 + 64;
    const int r1s = ch1 >> 2, k1s = (((ch1 & 3) ^ ((ch1 >> 3) & 3)) * 8);

    f32x4 acc[4][4];
    #pragma unroll
    for (int i = 0; i < 4; ++i)
        #pragma unroll
        for (int j = 0; j < 4; ++j) acc[i][j] = 0;

    const int fr  = lane & 15;
    const int fc  = lane >> 4;
    const int fsw = (fr >> 1) & 3;
    const int fo  = ((fc ^ fsw) * 8);

    for (int k0 = 0; k0 < K; k0 += 32){
        __builtin_amdgcn_global_load_lds((gvoid*)(Ae + (size_t)r0s * K + k0 + k0s),
                                         (lvoid*)(As + (wid * 2 + 0) * 512), 16, 0, 0);
        __builtin_amdgcn_global_load_lds((gvoid*)(Ae + (size_t)r1s * K + k0 + k1s),
                                         (lvoid*)(As + (wid * 2 + 1) * 512), 16, 0, 0);
        __builtin_amdgcn_global_load_lds((gvoid*)(Be + (size_t)r0s * K + k0 + k0s),
                                         (lvoid*)(Bs + (wid * 2 + 0) * 512), 16, 0, 0);
        __builtin_amdgcn_global_load_lds((gvoid*)(Be + (size_t)r1s * K + k0 + k1s),
                                         (lvoid*)(Bs + (wid * 2 + 1) * 512), 16, 0, 0);
        __syncthreads();

        bf16x8 af[4], bf[4];
        #pragma unroll
        for (int i = 0; i < 4; ++i)
            af[i] = *(const bf16x8*)(As + (wm * 64 + i * 16 + fr) * 32 + fo);
        #pragma unroll
        for (int j = 0; j < 4; ++j)
            bf[j] = *(const bf16x8*)(Bs + (wn * 64 + j * 16 + fr) * 32 + fo);
        #pragma unroll
        for (int i = 0; i < 4; ++i)
            #pragma unroll
            for (int j = 0; j < 4; ++j)
                acc[i][j] = __builtin_amdgcn_mfma_f32_16x16x32_bf16(af[i], bf[j], acc[i][j], 0, 0, 0);
        __syncthreads();
    }

    const int row0 = m0 + wm * 64, col0 = n0 + wn * 64;
    const size_t cb = (size_t)e * (size_t)M * N;
    #pragma unroll
    for (int j = 0; j < 4; ++j){
        const int col = col0 + j * 16 + (lane & 15);
        const float bv = bias[(size_t)e * N + col];
        #pragma unroll
        for (int i = 0; i < 4; ++i){
            const int rbase = row0 + i * 16 + (lane >> 4) * 4;
            #pragma unroll
            for (int r = 0; r < 4; ++r){
                float v = acc[i][j][r] + bv;
                v = fmaxf(v, 0.0f);
                Cout[cb + (size_t)(rbase + r) * N + col] = f2bf(v);
            }
        }
    }
}

// ================= 256x256 8-phase double-buffered bf16 GEMM (layer 1) =================
// 512 threads = 8 waves (2M x 4N); per-wave output 128x64 (INTERLEAVED fragments); BK=64.
// LDS 128 KiB: A bufs smem+{0,32768}; B bufs smem+{65536,98304}; each 256 rows x 64 cols bf16
// (row = 128 B = exact 32-bank wrap).
// Fragment interleave (race-alignment fix): wave-local M-frag mi -> global gm = mi*2 + wm;
//   N-frag nj -> gn = nj*4 + wn.  Then LOAD_A(buf,mh) reads EXACTLY rows [mh*128, mh*128+128)
//   (= staging half mh) across all waves, and LOAD_B(buf,nh) exactly half nh.  This makes the
//   stage-after-last-read ledger below valid (round-1 bug: contiguous mapping spanned both
//   staging halves every phase -> staging raced with reads -> absmax 1.95).
// LDS swizzle (involution, both sides): 16B chunk c of row r lives at chunk (c ^ (r&7)).
//   ds_read_b128 reads then spread 64 lanes uniformly 8-per-16B-granule-column: conflict-free.
// Schedule: 8 phases / 2 K-tiles per iter; 1 half-tile stage per phase; vmcnt(6) at phases
//   4 & 8 only (retires exactly the next tile's 8 loads); raw s_barrier + manual lgkmcnt;
//   setprio(1) around each 16-MFMA quadrant.
// Region ledger (buf0 pass = ph1..4): A0 last read ph1 -> staged ph2; B1 ph2 -> ph3;
//   A1 ph3 -> ph4; B0 ph4 -> ph5; mirrored for buf1 at ph5..8/ph1.
#define PH_BAR()  asm volatile("s_barrier" ::: "memory")
#define PH_LGKM() asm volatile("s_waitcnt lgkmcnt(0)" ::: "memory")

#define LOAD_A(SB, mh) do{ \
    _Pragma("unroll") \
    for (int i_ = 0; i_ < 4; ++i_){ \
        const char* p_ = (SB) + aRowBase + (mh) * 16384 + i_ * 4096; \
        a_[i_][0] = *(const bf16x8*)(p_ + coff0); \
        a_[i_][1] = *(const bf16x8*)(p_ + coff1); \
    } \
}while(0)

#define LOAD_B(SB, nh) do{ \
    _Pragma("unroll") \
    for (int j_ = 0; j_ < 2; ++j_){ \
        const char* p_ = (SB) + bRowBase + (nh) * 16384 + j_ * 8192; \
        b_[j_][0] = *(const bf16x8*)(p_ + coff0); \
        b_[j_][1] = *(const bf16x8*)(p_ + coff1); \
    } \
}while(0)

#define MFMA_Q(mh, nh) do{ \
    __builtin_amdgcn_s_setprio(1); \
    _Pragma("unroll") \
    for (int i_ = 0; i_ < 4; ++i_){ \
        _Pragma("unroll") \
        for (int j_ = 0; j_ < 2; ++j_){ \
            acc[(mh)*4 + i_][(nh)*2 + j_] = __builtin_amdgcn_mfma_f32_16x16x32_bf16( \
                a_[i_][0], b_[j_][0], acc[(mh)*4 + i_][(nh)*2 + j_], 0, 0, 0); \
            acc[(mh)*4 + i_][(nh)*2 + j_] = __builtin_amdgcn_mfma_f32_16x16x32_bf16( \
                a_[i_][1], b_[j_][1], acc[(mh)*4 + i_][(nh)*2 + j_], 0, 0, 0); \
        } \
    } \
    __builtin_amdgcn_s_setprio(0); \
}while(0)

__global__ __launch_bounds__(512) void gemm256_bt_relu(const unsigned short* __restrict__ A,
                                                       long long aEstride,
                                                       const unsigned short* __restrict__ Bt,
                                                       const float* __restrict__ bias,
                                                       unsigned short* __restrict__ Cout,
                                                       int M, int N, int K){
    extern __shared__ char smem[];
    const int e  = blockIdx.z;
    const int m0 = blockIdx.y * 256, n0 = blockIdx.x * 256;
    const int tid = threadIdx.x, lane = tid & 63, wid = tid >> 6;
    const int wm = wid >> 2, wn = wid & 3;

    const unsigned short* Ae = A + (size_t)e * (size_t)aEstride + (size_t)m0 * K;
    const unsigned short* Be = Bt + (size_t)e * (size_t)N * K + (size_t)n0 * K;

    // staging: lane covers row (wid*16 + srow [+8]), 16B chunk sc8 (pre-swizzled source)
    const int srow = lane >> 3;
    const int sc8  = (lane & 7) ^ srow;

    // fragment addressing: operand row-in-subtile fr = lane&15, k-chunk fc = lane>>4
    const int fr = lane & 15, fc = lane >> 4;
    const int coff0 = (fc ^ (fr & 7)) << 4;   // ks=0 chunk, swizzled
    const int coff1 = coff0 ^ 64;             // ks=1: chunk+4 -> byte ^64
    const int aRowBase = (wm * 16 + fr) << 7; // row = gm*16+fr = mh*128 + i*32 + wm*16 + fr
    const int bRowBase = (wn * 16 + fr) << 7; // row = gn*16+fr = nh*128 + j*64 + wn*16 + fr

    const char* sA0 = smem;
    const char* sA1 = smem + 32768;
    const char* sB0 = smem + 65536;
    const char* sB1 = smem + 98304;

    auto STAGE = [&](int tt, int h){
        const int buf = tt & 1;
        const unsigned short* g;
        char* l;
        if (h < 2){   // A half-tile h: rows h*128 .. +127
            g = Ae + (size_t)(h * 128 + wid * 16 + srow) * (size_t)K + (size_t)tt * 64 + sc8 * 8;
            l = smem + buf * 32768 + h * 16384 + wid * 2048;
        } else {      // B half-tile h-2
            g = Be + (size_t)((h - 2) * 128 + wid * 16 + srow) * (size_t)K + (size_t)tt * 64 + sc8 * 8;
            l = smem + 65536 + buf * 32768 + (h - 2) * 16384 + wid * 2048;
        }
        __builtin_amdgcn_global_load_lds((gvoid*)g, (lvoid*)l, 16, 0, 0);
        __builtin_amdgcn_global_load_lds((gvoid*)(g + (size_t)8 * K), (lvoid*)(l + 1024), 16, 0, 0);
    };

    f32x4 acc[8][4];
    #pragma unroll
    for (int i = 0; i < 8; ++i)
        #pragma unroll
        for (int j = 0; j < 4; ++j) acc[i][j] = 0;

    bf16x8 a_[4][2], b_[2][2];

    const int NT = K >> 6;        // K-tiles of 64

    // prologue: tile0 fully, tile1 half-tiles {0,3,1} -> vmcnt(6) retires exactly tile0
    STAGE(0, 0); STAGE(0, 1); STAGE(0, 2); STAGE(0, 3);
    STAGE(1, 0); STAGE(1, 3); STAGE(1, 1);
    asm volatile("s_waitcnt vmcnt(6)" ::: "memory");
    PH_BAR();

    #pragma unroll 1
    for (int it = 0; it < (NT >> 1); ++it){
        const int T  = it * 2;
        const int t2 = (T + 2 < NT) ? T + 2 : T + 2 - NT;   // wrap: harmless prefetch
        const int t3 = (T + 3 < NT) ? T + 3 : T + 3 - NT;

        // ---- phase 1: quad(0,0) from buf0 ----
        LOAD_A(sA0, 0); LOAD_B(sB0, 0);
        STAGE(T + 1, 2);                 // B0 of buf1 (last read prev ph8)
        PH_BAR(); PH_LGKM();
        MFMA_Q(0, 0);
        PH_BAR();
        // ---- phase 2: quad(0,1), reuse A ----
        LOAD_B(sB0, 1);
        STAGE(t2, 0);                    // A0 of buf0 (last read ph1)
        PH_BAR(); PH_LGKM();
        MFMA_Q(0, 1);
        PH_BAR();
        // ---- phase 3: quad(1,1), reuse B ----
        LOAD_A(sA0, 1);
        STAGE(t2, 3);                    // B1 of buf0 (last read ph2)
        PH_BAR(); PH_LGKM();
        MFMA_Q(1, 1);
        PH_BAR();
        // ---- phase 4: quad(1,0), reuse A ----
        LOAD_B(sB0, 0);
        STAGE(t2, 1);                    // A1 of buf0 (last read ph3)
        PH_BAR(); PH_LGKM();
        MFMA_Q(1, 0);
        asm volatile("s_waitcnt vmcnt(6)" ::: "memory");   // tile T+1 fully landed
        PH_BAR();
        // ---- phase 5: quad(0,0) from buf1 ----
        LOAD_A(sA1, 0); LOAD_B(sB1, 0);
        STAGE(t2, 2);                    // B0 of buf0 (last read ph4)
        PH_BAR(); PH_LGKM();
        MFMA_Q(0, 0);
        PH_BAR();
        // ---- phase 6 ----
        LOAD_B(sB1, 1);
        STAGE(t3, 0);                    // A0 of buf1 (last read ph5)
        PH_BAR(); PH_LGKM();
        MFMA_Q(0, 1);
        PH_BAR();
        // ---- phase 7 ----
        LOAD_A(sA1, 1);
        STAGE(t3, 3);                    // B1 of buf1 (last read ph6)
        PH_BAR(); PH_LGKM();
        MFMA_Q(1, 1);
        PH_BAR();
        // ---- phase 8 ----
        LOAD_B(sB1, 0);
        STAGE(t3, 1);                    // A1 of buf1 (last read ph7)
        PH_BAR(); PH_LGKM();
        MFMA_Q(1, 0);
        asm volatile("s_waitcnt vmcnt(6)" ::: "memory");   // tile T+2 fully landed
        PH_BAR();
    }

    asm volatile("s_waitcnt vmcnt(0)" ::: "memory");   // drain tail prefetches

    // epilogue: bias + relu, bf16 store. C/D layout: col=lane&15, row=(lane>>4)*4+reg.
    // Interleaved fragments: global M-frag = mi*2 + wm, global N-frag = nj*4 + wn.
    const size_t cb = (size_t)e * (size_t)M * N;
    #pragma unroll
    for (int nj = 0; nj < 4; ++nj){
        const int col = n0 + (nj * 4 + wn) * 16 + fr;
        const float bv = bias[(size_t)e * N + col];
        #pragma unroll
        for (int mi = 0; mi < 8; ++mi){
            const int rb = m0 + (mi * 2 + wm) * 16 + fc * 4;
            #pragma unroll
            for (int r = 0; r < 4; ++r){
                float v = acc[mi][nj][r] + bv;
                v = fmaxf(v, 0.0f);
                Cout[cb + (size_t)(rb + r) * N + col] = f2bf(v);
            }
        }
    }
}

// ---------------- layer 3 ----------------
__global__ __launch_bounds__(256) void layer3_kernel(const unsigned short* __restrict__ h2,
                                                     const float* __restrict__ W3,
                                                     const float* __restrict__ b3,
                                                     float* __restrict__ out){
    const int w     = blockIdx.x * 4 + (threadIdx.x >> 6);
    const int lane  = threadIdx.x & 63;
    const int rbase = w * 16;
    const int e     = rbase >> 10;
    const float4 wv = *(const float4*)(W3 + (size_t)e * H2_ + lane * 4);
    const float  bv = b3[e];
    #pragma unroll
    for (int i = 0; i < 16; ++i){
        const int r = rbase + i;
        const uint2 hv = *(const uint2*)(h2 + (size_t)r * H2_ + lane * 4);
        float sum = bf2f(hv.x & 0xffffu) * wv.x
                  + bf2f(hv.x >> 16)     * wv.y
                  + bf2f(hv.y & 0xffffu) * wv.z
                  + bf2f(hv.y >> 16)     * wv.w;
        #pragma unroll
        for (int o = 32; o > 0; o >>= 1) sum += __shfl_down(sum, o, 64);
        if (lane == 0) out[(size_t)(r & 1023) * E_ + e] = sum + bv;
    }
}

extern "C" void kernel_launch(void* const* d_in, const int* in_sizes, int n_in,
                              void* d_out, int out_size, void* d_ws, size_t ws_size,
                              hipStream_t stream){
    const float* x  = (const float*)d_in[0];
    const float* W1 = (const float*)d_in[1];
    const float* b1 = (const float*)d_in[2];
    const float* W2 = (const float*)d_in[3];
    const float* b2 = (const float*)d_in[4];
    const float* W3 = (const float*)d_in[5];
    const float* b3 = (const float*)d_in[6];
    float* out = (float*)d_out;

    char* ws = (char*)d_ws;
    const size_t szW1t = (size_t)E_ * H1_ * D_ * 2;   // 209,715,200 B
    const size_t szW2t = (size_t)E_ * H2_ * H1_ * 2;  //  26,214,400 B
    const size_t szXb  = (size_t)B_ * D_ * 2;         //   4,194,304 B
    unsigned short* W1t = (unsigned short*)(ws);
    unsigned short* W2t = (unsigned short*)(ws + szW1t);
    unsigned short* xb  = (unsigned short*)(ws + szW1t + szW2t);
    unsigned short* h1  = (unsigned short*)(ws + szW1t + szW2t + szXb);
    unsigned short* h2  = (unsigned short*)(ws);      // aliases W1t (dead after gemm1)

    static bool smem_attr = false;
    if (!smem_attr){
        (void)hipFuncSetAttribute(reinterpret_cast<const void*>(gemm256_bt_relu),
                                  hipFuncAttributeMaxDynamicSharedMemorySize, 131072);
        smem_attr = true;
    }

    cvt_x_kernel<<<(B_ * D_) / (256 * 4), 256, 0, stream>>>(x, xb);
    transpose_cvt_kernel<<<dim3(H1_ / 64, D_ / 64, E_), 256, 0, stream>>>(W1, W1t, D_, H1_);
    transpose_cvt_kernel<<<dim3(H2_ / 64, H1_ / 64, E_), 256, 0, stream>>>(W2, W2t, H1_, H2_);
    gemm256_bt_relu<<<dim3(H1_ / 256, B_ / 256, E_), 512, 131072, stream>>>(xb, 0, W1t, b1, h1, B_, H1_, D_);
    gemm_bt_relu<<<dim3(H2_ / 128, B_ / 128, E_), 256, 0, stream>>>(h1, (long long)B_ * H1_, W2t, b2, h2, B_, H2_, H1_);
    layer3_kernel<<<(E_ * B_) / 64, 256, 0, stream>>>(h2, W3, b3, out);
}